// Round 13
// baseline (918.771 us; speedup 1.0000x reference)
//
#include <hip/hip_runtime.h>
#include <hip/hip_bf16.h>

constexpr int N_NODES = 100000;
constexpr int N_EDGES = 3200000;
constexpr int N_PAIRS = 500000;
constexpr int D       = 256;
constexpr int NRANGE  = 8;
constexpr int RSPAN   = 12500;            // nodes per dst-range
constexpr int SCANN   = 100352;           // 98*1024, padded node count
constexpr int RCAP    = 410000;           // bucket capacity per range

using frag_ab = __attribute__((ext_vector_type(8))) short;
using frag_cd = __attribute__((ext_vector_type(4))) float;
typedef unsigned short ushort8 __attribute__((ext_vector_type(8)));

static __device__ __forceinline__ float b2f(unsigned short u) {
  return __uint_as_float(((unsigned)u) << 16);
}
static __device__ __forceinline__ unsigned short f2bf(float f) {
  unsigned u = __float_as_uint(f);
  unsigned r = (u + 0x7fff + ((u >> 16) & 1)) >> 16;   // RNE
  return (unsigned short)r;
}

// ---------------------------------------------------------------------------
// Role-split kernel: blocks [0, PART_BLOCKS) run partition+hist over ei;
// blocks [PART_BLOCKS, +CONV_BLOCKS) convert x/W1/W2 to bf16. The two roles
// touch disjoint data and run concurrently (saves the shorter from the
// critical path). counts and rc are pre-zeroed via hipMemsetAsync.
// ---------------------------------------------------------------------------
constexpr int PART_SEG    = 4096;
constexpr int PART_BLOCKS = (N_EDGES + PART_SEG - 1) / PART_SEG;   // 782
constexpr int CONV_BLOCKS = 4096;

__global__ __launch_bounds__(256) void conv_part(const int* __restrict__ ei,
                                                 int* __restrict__ counts,
                                                 int* __restrict__ rc,
                                                 int* __restrict__ bucket,
                                                 const float4* __restrict__ x,
                                                 const float4* __restrict__ W1,
                                                 const float4* __restrict__ W2,
                                                 ushort4* __restrict__ xb,
                                                 ushort4* __restrict__ W1b,
                                                 ushort4* __restrict__ W2b, int n4x) {
  const int t = threadIdx.x;
  if (blockIdx.x < PART_BLOCKS) {
    // --- partition + histogram role ---
    __shared__ int lcnt[NRANGE];
    __shared__ int lbase[NRANGE];
    const int base = blockIdx.x * PART_SEG;
    if (t < NRANGE) lcnt[t] = 0;
    __syncthreads();

    int rnk[16], rng[16], pv[16];
#pragma unroll
    for (int j = 0; j < 16; ++j) {
      const int i = base + j * 256 + t;
      if (i < N_EDGES) {
        const int sv = ei[i];
        const int dv = ei[N_EDGES + i];
        atomicAdd(&counts[dv], 1);
        rng[j] = dv / RSPAN;
        pv[j] = sv | ((dv - rng[j] * RSPAN) << 17);
        rnk[j] = atomicAdd(&lcnt[rng[j]], 1);
      } else rng[j] = -1;
    }
    __syncthreads();
    if (t < NRANGE) lbase[t] = t * RCAP + atomicAdd(&rc[t], lcnt[t]);
    __syncthreads();
#pragma unroll
    for (int j = 0; j < 16; ++j) {
      if (rng[j] >= 0) bucket[lbase[rng[j]] + rnk[j]] = pv[j];
    }
  } else {
    // --- convert role ---
    const int nconv = n4x + 2 * 16384;
    int i = (blockIdx.x - PART_BLOCKS) * 256 + t;
    const int stride = CONV_BLOCKS * 256;
    for (; i < nconv; i += stride) {
      float4 v; ushort4* dst; int k;
      if (i < n4x) { v = x[i]; dst = xb; k = i; }
      else if (i < n4x + 16384) { k = i - n4x; v = W1[k]; dst = W1b; }
      else { k = i - n4x - 16384; v = W2[k]; dst = W2b; }
      ushort4 o;
      o.x = f2bf(v.x); o.y = f2bf(v.y); o.z = f2bf(v.z); o.w = f2bf(v.w);
      dst[k] = o;
    }
  }
}

// --- hierarchical exclusive scan over SCANN ints ----------------------------
__global__ __launch_bounds__(1024) void scan_block_k(const int* __restrict__ in,
                                                     int* __restrict__ out,
                                                     int* __restrict__ bsum) {
  __shared__ int wsum[16];
  const int t = threadIdx.x, lane = t & 63, w = t >> 6;
  const int gid = blockIdx.x * 1024 + t;
  const int v = in[gid];
  int s = v;
#pragma unroll
  for (int off = 1; off < 64; off <<= 1) {
    int u = __shfl_up(s, off, 64);
    if (lane >= off) s += u;
  }
  if (lane == 63) wsum[w] = s;
  __syncthreads();
  if (t < 16) {
    int ws = wsum[t];
#pragma unroll
    for (int off = 1; off < 16; off <<= 1) {
      int u = __shfl_up(ws, off, 64);
      if (lane >= off) ws += u;
    }
    wsum[t] = ws;
  }
  __syncthreads();
  const int wpre = (w == 0) ? 0 : wsum[w - 1];
  out[gid] = wpre + s - v;               // block-local exclusive
  if (t == 1023) bsum[blockIdx.x] = wsum[15];
}

// add block offsets; each block redundantly computes the tiny 98-int scan
constexpr int SCAN_BLOCKS = SCANN / 1024;   // 98
__global__ __launch_bounds__(1024) void scan_addf(int* __restrict__ cursor,
                                                  const int* __restrict__ bsum) {
  __shared__ int bs[SCAN_BLOCKS];
  __shared__ int bs2[SCAN_BLOCKS];
  const int t = threadIdx.x;
  if (t < SCAN_BLOCKS) bs[t] = bsum[t];
  __syncthreads();
  if (t == 0) {
    int run = 0;
#pragma unroll 1
    for (int k = 0; k < SCAN_BLOCKS; ++k) { bs2[k] = run; run += bs[k]; }
  }
  __syncthreads();
  const int gid = blockIdx.x * 1024 + t;
  cursor[gid] += bs2[blockIdx.x];
}

// --- per-range local fill; slot via atomicSub on counts (counts dead after) -
constexpr int FLB = 128;   // blocks per range
__global__ __launch_bounds__(256) void fill_local(const int* __restrict__ bucket,
                                                  const int* __restrict__ rc,
                                                  const int* __restrict__ cursor,
                                                  int* __restrict__ counts,
                                                  int* __restrict__ csr) {
  const int r = blockIdx.x & 7;
  const int j = blockIdx.x >> 3;
  const int rbase = r * RSPAN;
  const int beg = r * RCAP;
  const int end = beg + rc[r];
  for (int i = beg + j * 256 + threadIdx.x; i < end; i += FLB * 256) {
    const int e = bucket[i];
    const int src = e & 0x1FFFF;
    const int dst = rbase + (e >> 17);
    const int p = cursor[dst] + atomicSub(&counts[dst], 1) - 1;
    csr[p] = src;
  }
}

// out[node] = x[node] + sum_{s in csr} x[s]; bf16 rows, f32 accumulate.
// Segment bounds from cursor[node], cursor[node+1] (padded scan => valid).
__global__ __launch_bounds__(256) void gather_agg_bf16(const ushort* __restrict__ x,
                                                       const int* __restrict__ csr,
                                                       const int* __restrict__ cursor,
                                                       ushort* __restrict__ out) {
  const int node = blockIdx.x * 4 + (threadIdx.x >> 6);
  const int lane = threadIdx.x & 63;
  const int half = lane >> 5;
  const int fl   = lane & 31;
  if (node >= N_NODES) return;
  const int beg = cursor[node];
  const int end = cursor[node + 1];
  const size_t fo = (size_t)fl * 8;

  float acc[8];
#pragma unroll
  for (int j = 0; j < 8; ++j) acc[j] = 0.f;

  if (half == 0) {
    const ushort8 self = *reinterpret_cast<const ushort8*>(x + (size_t)node * D + fo);
#pragma unroll
    for (int j = 0; j < 8; ++j) acc[j] += b2f(self[j]);
  }

  int o = beg + half;
  for (; o + 6 < end; o += 8) {
    const int s0 = csr[o], s1 = csr[o + 2], s2 = csr[o + 4], s3 = csr[o + 6];
    const ushort8 v0 = *reinterpret_cast<const ushort8*>(x + (size_t)s0 * D + fo);
    const ushort8 v1 = *reinterpret_cast<const ushort8*>(x + (size_t)s1 * D + fo);
    const ushort8 v2 = *reinterpret_cast<const ushort8*>(x + (size_t)s2 * D + fo);
    const ushort8 v3 = *reinterpret_cast<const ushort8*>(x + (size_t)s3 * D + fo);
#pragma unroll
    for (int j = 0; j < 8; ++j)
      acc[j] += (b2f(v0[j]) + b2f(v1[j])) + (b2f(v2[j]) + b2f(v3[j]));
  }
  for (; o < end; o += 2) {
    const ushort8 v = *reinterpret_cast<const ushort8*>(x + (size_t)csr[o] * D + fo);
#pragma unroll
    for (int j = 0; j < 8; ++j) acc[j] += b2f(v[j]);
  }

#pragma unroll
  for (int j = 0; j < 8; ++j) acc[j] += __shfl_xor(acc[j], 32, 64);

  if (half == 0) {
    ushort8 ov;
#pragma unroll
    for (int j = 0; j < 8; ++j) ov[j] = f2bf(acc[j]);
    *reinterpret_cast<ushort8*>(out + (size_t)node * D + fo) = ov;
  }
}

// ---------------------------------------------------------------------------
// GEMM core. 1-D grid of 6252 with bijective XCD-chunk swizzle (R12-proven).
// ---------------------------------------------------------------------------
constexpr int GEMM_NWG = ((N_NODES + 63) / 64) * 4;   // 6252
constexpr int GEMM_Q   = GEMM_NWG / 8;                // 781
constexpr int GEMM_R   = GEMM_NWG % 8;                // 4
constexpr int CT_PITCH = 72;

template <bool WRITE_C>
__global__ __launch_bounds__(256) void gemm_mfma(const ushort* __restrict__ A,
                                                 const ushort* __restrict__ W,
                                                 const float* __restrict__ bias,
                                                 ushort* __restrict__ C,
                                                 const float* __restrict__ W3,
                                                 float* __restrict__ projp,
                                                 int M) {
  __shared__ __align__(16) ushort As[64 * 256];
  __shared__ __align__(16) ushort Ws[64 * 256];

  const int orig = blockIdx.x;
  const int xcd  = orig & 7;
  const int jj   = orig >> 3;
  const int base_ = (xcd < GEMM_R) ? xcd * (GEMM_Q + 1)
                                   : GEMM_R * (GEMM_Q + 1) + (xcd - GEMM_R) * GEMM_Q;
  const int swz  = base_ + jj;
  const int row0 = (swz >> 2) * 64;
  const int col0 = (swz & 3) * 64;
  const int ct   = swz & 3;

  const int t = threadIdx.x;
  const int w = t >> 6, l = t & 63;

  {
    const float4 zero4 = {0.f, 0.f, 0.f, 0.f};
#pragma unroll
    for (int i = 0; i < 8; ++i) {
      const int chunk = t + i * 256;
      const int r  = chunk >> 5;
      const int kb = (chunk & 31) << 4;
      const int swzb = kb ^ ((r & 7) << 4);
      const int grow = row0 + r;
      float4 av = zero4;
      if (grow < M)
        av = *reinterpret_cast<const float4*>(
            reinterpret_cast<const char*>(A) + (size_t)grow * 512 + kb);
      *reinterpret_cast<float4*>(reinterpret_cast<char*>(As) + r * 512 + swzb) = av;
      const float4 wv = *reinterpret_cast<const float4*>(
          reinterpret_cast<const char*>(W) + (size_t)(col0 + r) * 512 + kb);
      *reinterpret_cast<float4*>(reinterpret_cast<char*>(Ws) + r * 512 + swzb) = wv;
    }
  }
  __syncthreads();

  const int g  = l >> 4;
  const int fr = l & 15;

  frag_cd acc[4];
#pragma unroll
  for (int c = 0; c < 4; ++c) {
    acc[c][0] = 0.f; acc[c][1] = 0.f; acc[c][2] = 0.f; acc[c][3] = 0.f;
  }

  const int arow = w * 16 + fr;
  const char* Asb = reinterpret_cast<const char*>(As);
  const char* Wsb = reinterpret_cast<const char*>(Ws);
#pragma unroll
  for (int ks = 0; ks < 8; ++ks) {
    const int kb = ks * 64 + g * 16;
    const frag_ab af = *reinterpret_cast<const frag_ab*>(
        Asb + arow * 512 + (kb ^ ((arow & 7) << 4)));
#pragma unroll
    for (int c = 0; c < 4; ++c) {
      const int wrow = c * 16 + fr;
      const frag_ab bf = *reinterpret_cast<const frag_ab*>(
          Wsb + wrow * 512 + (kb ^ ((wrow & 7) << 4)));
      acc[c] = __builtin_amdgcn_mfma_f32_16x16x32_bf16(af, bf, acc[c], 0, 0, 0);
    }
  }
  __syncthreads();

  ushort* Ct = As;
#pragma unroll
  for (int c = 0; c < 4; ++c) {
    const int col = c * 16 + fr;
    const float bv = bias[col0 + col];
#pragma unroll
    for (int r = 0; r < 4; ++r) {
      const int rl = w * 16 + g * 4 + r;
      Ct[rl * CT_PITCH + col] = f2bf(fmaxf(acc[c][r] + bv, 0.f));
    }
  }
  __syncthreads();

  if constexpr (WRITE_C) {
#pragma unroll
    for (int i = 0; i < 2; ++i) {
      const int chunk = t + i * 256;
      const int r  = chunk >> 3;
      const int cb = (chunk & 7) << 4;
      const int grow = row0 + r;
      if (grow < M)
        *reinterpret_cast<float4*>(reinterpret_cast<char*>(C) + (size_t)grow * 512 + col0 * 2 + cb) =
            *reinterpret_cast<const float4*>(
                reinterpret_cast<const char*>(Ct) + r * (CT_PITCH * 2) + cb);
    }
  } else {
    const int r = t >> 2;
    const int q = t & 3;
    const int grow = row0 + r;
    float pa0 = 0.f, pa1 = 0.f, pb0 = 0.f, pb1 = 0.f;
    if (grow < M) {
      const ushort8 u8a = *reinterpret_cast<const ushort8*>(&Ct[r * CT_PITCH + q * 16]);
      const ushort8 u8b = *reinterpret_cast<const ushort8*>(&Ct[r * CT_PITCH + q * 16 + 8]);
#pragma unroll
      for (int j = 0; j < 16; ++j) {
        const float hv = b2f(j < 8 ? u8a[j] : u8b[j - 8]);
        const int gc = col0 + q * 16 + j;
        pa0 += hv * W3[gc];
        pa1 += hv * W3[512 + gc];
        pb0 += hv * W3[256 + gc];
        pb1 += hv * W3[768 + gc];
      }
    }
    pa0 += __shfl_xor(pa0, 1, 64); pa0 += __shfl_xor(pa0, 2, 64);
    pa1 += __shfl_xor(pa1, 1, 64); pa1 += __shfl_xor(pa1, 2, 64);
    pb0 += __shfl_xor(pb0, 1, 64); pb0 += __shfl_xor(pb0, 2, 64);
    pb1 += __shfl_xor(pb1, 1, 64); pb1 += __shfl_xor(pb1, 2, 64);
    if (q == 0 && grow < M) {
      float4 o; o.x = pa0; o.y = pa1; o.z = pb0; o.w = pb1;
      *reinterpret_cast<float4*>(&projp[((size_t)ct * N_NODES + grow) * 4]) = o;
    }
  }
}

// pair head directly from the 4 projp slices (proj_reduce fused in)
__global__ __launch_bounds__(256) void pair_fused(const float4* __restrict__ projp,
                                                  const int* __restrict__ idx,
                                                  const float* __restrict__ b3,
                                                  float* __restrict__ out) {
  const int p = blockIdx.x * blockDim.x + threadIdx.x;
  if (p >= N_PAIRS) return;
  const int2 ii = reinterpret_cast<const int2*>(idx)[p];
  float l0 = b3[0], l1 = b3[1];
#pragma unroll
  for (int ct = 0; ct < 4; ++ct) {
    const float4 pa = projp[(size_t)ct * N_NODES + ii.x];
    const float4 pb = projp[(size_t)ct * N_NODES + ii.y];
    l0 += pa.x + pb.z;
    l1 += pa.y + pb.w;
  }
  const float m = fmaxf(l0, l1);
  const float lse = m + logf(expf(l0 - m) + expf(l1 - m));
  float2 o; o.x = l0 - lse; o.y = l1 - lse;
  reinterpret_cast<float2*>(out)[p] = o;
}

// ---------------------------------------------------------------------------
extern "C" void kernel_launch(void* const* d_in, const int* in_sizes, int n_in,
                              void* d_out, int out_size, void* d_ws, size_t ws_size,
                              hipStream_t stream) {
  const float* x   = (const float*)d_in[0];
  const int*   ei  = (const int*)d_in[1];
  const int*   idx = (const int*)d_in[2];
  const float* W1  = (const float*)d_in[3];
  const float* b1  = (const float*)d_in[4];
  const float* W2  = (const float*)d_in[5];
  const float* b2  = (const float*)d_in[6];
  const float* W3  = (const float*)d_in[7];
  const float* b3  = (const float*)d_in[8];
  float* out = (float*)d_out;

  char* ws = (char*)d_ws;
  ushort* xb    = (ushort*)(ws);                   // 51.2 MB
  ushort* aggb  = (ushort*)(ws + 51200000);        // 51.2 MB
  int*    bucket= (int*)(ws + 51200000);           // 13.12 MB, aliases aggb (build only)
  ushort* hb    = (ushort*)(ws + 102400000);       // 51.2 MB
  float* projp  = (float*)(ws + 102400000);        // 6.4 MB, aliases hb (gemm2 output)
  ushort* W1b   = (ushort*)(ws + 153600000);       // 128 KB
  ushort* W2b   = (ushort*)(ws + 153731072);       // 128 KB
  int* counts   = (int*)(ws + 153862144);          // SCANN ints
  int* cursor   = (int*)(ws + 154263552);          // SCANN+ ints
  int* csr      = (int*)(ws + 155066368);          // 12.8 MB
  int* bsum     = (int*)(ws + 169466368);          // 98 ints
  int* rc       = (int*)(ws + 169467392);          // 8 ints

  const dim3 blk(256);
  const size_t feat = (size_t)N_NODES * D;
  const dim3 cpGrid(PART_BLOCKS + CONV_BLOCKS);    // 4878, role-split
  const dim3 flocGrid(NRANGE * FLB);               // 1024
  const dim3 nodeGrid((N_NODES + 3) / 4);
  const dim3 gemmGrid(GEMM_NWG);                   // 6252, swizzled
  const dim3 pairGrid((N_PAIRS + 255) / 256);

  // ---- zero counts + rc (stream-ordered, capture-safe) ----
  hipMemsetAsync(counts, 0, (size_t)SCANN * 4, stream);
  hipMemsetAsync(rc, 0, NRANGE * 4, stream);

  // ---- fused: convert (x,W1,W2) ∥ partition+hist ----
  conv_part<<<cpGrid, blk, 0, stream>>>(ei, counts, rc, bucket,
                                        (const float4*)x, (const float4*)W1,
                                        (const float4*)W2, (ushort4*)xb,
                                        (ushort4*)W1b, (ushort4*)W2b, (int)(feat / 4));

  // ---- scan + fill ----
  scan_block_k<<<dim3(SCAN_BLOCKS), dim3(1024), 0, stream>>>(counts, cursor, bsum);
  scan_addf<<<dim3(SCAN_BLOCKS), dim3(1024), 0, stream>>>(cursor, bsum);
  fill_local<<<flocGrid, blk, 0, stream>>>(bucket, rc, cursor, counts, csr);

  // ---- layer 1 ----
  gather_agg_bf16<<<nodeGrid, blk, 0, stream>>>(xb, csr, cursor, aggb);
  gemm_mfma<true><<<gemmGrid, blk, 0, stream>>>(aggb, W1b, b1, hb, nullptr, nullptr, N_NODES);

  // ---- layer 2 (fused head projection) ----
  gather_agg_bf16<<<nodeGrid, blk, 0, stream>>>(hb, csr, cursor, aggb);
  gemm_mfma<false><<<gemmGrid, blk, 0, stream>>>(aggb, W2b, b2, nullptr, W3, projp, N_NODES);

  // ---- pair head ----
  pair_fused<<<pairGrid, blk, 0, stream>>>((const float4*)projp, idx, b3, out);
}

// Round 14
// 896.404 us; speedup vs baseline: 1.0250x; 1.0250x over previous
//
#include <hip/hip_runtime.h>
#include <hip/hip_bf16.h>

constexpr int N_NODES = 100000;
constexpr int N_EDGES = 3200000;
constexpr int N_PAIRS = 500000;
constexpr int D       = 256;
constexpr int NRANGE  = 8;
constexpr int RSPAN   = 12500;            // nodes per dst-range
constexpr int SCANN   = 100352;           // 98*1024, padded node count
constexpr int RCAP    = 410000;           // bucket capacity per range (mean+17sigma)

using frag_ab = __attribute__((ext_vector_type(8))) short;
using frag_cd = __attribute__((ext_vector_type(4))) float;
typedef unsigned short ushort8 __attribute__((ext_vector_type(8)));

static __device__ __forceinline__ float b2f(unsigned short u) {
  return __uint_as_float(((unsigned)u) << 16);
}
static __device__ __forceinline__ unsigned short f2bf(float f) {
  unsigned u = __float_as_uint(f);
  unsigned r = (u + 0x7fff + ((u >> 16) & 1)) >> 16;   // RNE
  return (unsigned short)r;
}

// ---------------------------------------------------------------------------
// convert x, W1, W2 to bf16; zero counts; init rc — one launch
__global__ void conv_all(const float4* __restrict__ x, const float4* __restrict__ W1,
                         const float4* __restrict__ W2, ushort4* __restrict__ xb,
                         ushort4* __restrict__ W1b, ushort4* __restrict__ W2b,
                         int4* __restrict__ counts4, int* __restrict__ rc, int n4x) {
  const int nconv = n4x + 2 * 16384;
  const int total = nconv + SCANN / 4;
  int i = blockIdx.x * blockDim.x + threadIdx.x;
  if (i < NRANGE) rc[i] = i * RCAP;
  const int stride = gridDim.x * blockDim.x;
  for (; i < total; i += stride) {
    if (i < nconv) {
      float4 v; ushort4* dst; int k;
      if (i < n4x) { v = x[i]; dst = xb; k = i; }
      else if (i < n4x + 16384) { k = i - n4x; v = W1[k]; dst = W1b; }
      else { k = i - n4x - 16384; v = W2[k]; dst = W2b; }
      ushort4 o;
      o.x = f2bf(v.x); o.y = f2bf(v.y); o.z = f2bf(v.z); o.w = f2bf(v.w);
      dst[k] = o;
    } else {
      int4 z; z.x = 0; z.y = 0; z.z = 0; z.w = 0;
      counts4[i - nconv] = z;
    }
  }
}

// --- fused partition + histogram (one ei pass) ------------------------------
// bucket entry packs src (17 b) | dst_local (14 b); fixed range bases r*RCAP.
constexpr int PART_SEG = 4096;
__global__ __launch_bounds__(256) void part_hist(const int* __restrict__ ei,
                                                 int* __restrict__ counts,
                                                 int* __restrict__ rc,
                                                 int* __restrict__ bucket) {
  __shared__ int lcnt[NRANGE];
  __shared__ int lbase[NRANGE];
  const int t = threadIdx.x;
  const int base = blockIdx.x * PART_SEG;
  if (t < NRANGE) lcnt[t] = 0;
  __syncthreads();

  int rnk[16], rng[16], pv[16];
#pragma unroll
  for (int j = 0; j < 16; ++j) {
    const int i = base + j * 256 + t;
    if (i < N_EDGES) {
      const int sv = ei[i];
      const int dv = ei[N_EDGES + i];
      atomicAdd(&counts[dv], 1);
      rng[j] = dv / RSPAN;
      pv[j] = sv | ((dv - rng[j] * RSPAN) << 17);
      rnk[j] = atomicAdd(&lcnt[rng[j]], 1);
    } else rng[j] = -1;
  }
  __syncthreads();
  if (t < NRANGE) lbase[t] = atomicAdd(&rc[t], lcnt[t]);
  __syncthreads();
#pragma unroll
  for (int j = 0; j < 16; ++j) {
    if (rng[j] >= 0) bucket[lbase[rng[j]] + rnk[j]] = pv[j];
  }
}

// --- hierarchical exclusive scan over SCANN ints ----------------------------
__global__ __launch_bounds__(1024) void scan_block_k(const int* __restrict__ in,
                                                     int* __restrict__ out,
                                                     int* __restrict__ bsum) {
  __shared__ int wsum[16];
  const int t = threadIdx.x, lane = t & 63, w = t >> 6;
  const int gid = blockIdx.x * 1024 + t;
  const int v = in[gid];
  int s = v;
#pragma unroll
  for (int off = 1; off < 64; off <<= 1) {
    int u = __shfl_up(s, off, 64);
    if (lane >= off) s += u;
  }
  if (lane == 63) wsum[w] = s;
  __syncthreads();
  if (t < 16) {
    int ws = wsum[t];
#pragma unroll
    for (int off = 1; off < 16; off <<= 1) {
      int u = __shfl_up(ws, off, 64);
      if (lane >= off) ws += u;
    }
    wsum[t] = ws;
  }
  __syncthreads();
  const int wpre = (w == 0) ? 0 : wsum[w - 1];
  out[gid] = wpre + s - v;               // block-local exclusive
  if (t == 1023) bsum[blockIdx.x] = wsum[15];
}

__global__ __launch_bounds__(1024) void scan_small(const int* __restrict__ in,
                                                   int* __restrict__ out, int n) {
  __shared__ int wsum[16];
  const int t = threadIdx.x, lane = t & 63, w = t >> 6;
  int v = (t < n) ? in[t] : 0;
  int s = v;
#pragma unroll
  for (int off = 1; off < 64; off <<= 1) {
    int u = __shfl_up(s, off, 64);
    if (lane >= off) s += u;
  }
  if (lane == 63) wsum[w] = s;
  __syncthreads();
  if (t < 16) {
    int ws = wsum[t];
#pragma unroll
    for (int off = 1; off < 16; off <<= 1) {
      int u = __shfl_up(ws, off, 64);
      if (lane >= off) ws += u;
    }
    wsum[t] = ws;
  }
  __syncthreads();
  const int wpre = (w == 0) ? 0 : wsum[w - 1];
  if (t < n) out[t] = wpre + s - v;
}

__global__ __launch_bounds__(1024) void scan_add_k(int* __restrict__ cursor,
                                                   int* __restrict__ pos,
                                                   const int* __restrict__ bsum2) {
  const int gid = blockIdx.x * 1024 + threadIdx.x;
  const int v = cursor[gid] + bsum2[gid >> 10];
  cursor[gid] = v;
  pos[gid] = v;
}

// --- per-range local fill (reads only own bucket slice) ---------------------
constexpr int FLB = 128;   // blocks per range
__global__ __launch_bounds__(256) void fill_local(const int* __restrict__ bucket,
                                                  const int* __restrict__ rc,
                                                  int* __restrict__ pos,
                                                  int* __restrict__ csr) {
  const int r = blockIdx.x & 7;
  const int j = blockIdx.x >> 3;
  const int rbase = r * RSPAN;
  const int beg = r * RCAP;
  const int end = rc[r];
  for (int i = beg + j * 256 + threadIdx.x; i < end; i += FLB * 256) {
    const int e = bucket[i];
    const int src = e & 0x1FFFF;
    const int dst = rbase + (e >> 17);
    const int p = atomicAdd(&pos[dst], 1);
    csr[p] = src;
  }
}

// out[node] = x[node] + sum_{s in csr} x[s]; bf16 rows, f32 accumulate.
__global__ __launch_bounds__(256) void gather_agg_bf16(const ushort* __restrict__ x,
                                                       const int* __restrict__ csr,
                                                       const int* __restrict__ cursor,
                                                       const int* __restrict__ counts,
                                                       ushort* __restrict__ out) {
  const int node = blockIdx.x * 4 + (threadIdx.x >> 6);
  const int lane = threadIdx.x & 63;
  const int half = lane >> 5;
  const int fl   = lane & 31;
  if (node >= N_NODES) return;
  const int beg = cursor[node];
  const int end = beg + counts[node];
  const size_t fo = (size_t)fl * 8;

  float acc[8];
#pragma unroll
  for (int j = 0; j < 8; ++j) acc[j] = 0.f;

  if (half == 0) {
    const ushort8 self = *reinterpret_cast<const ushort8*>(x + (size_t)node * D + fo);
#pragma unroll
    for (int j = 0; j < 8; ++j) acc[j] += b2f(self[j]);
  }

  int o = beg + half;
  for (; o + 6 < end; o += 8) {
    const int s0 = csr[o], s1 = csr[o + 2], s2 = csr[o + 4], s3 = csr[o + 6];
    const ushort8 v0 = *reinterpret_cast<const ushort8*>(x + (size_t)s0 * D + fo);
    const ushort8 v1 = *reinterpret_cast<const ushort8*>(x + (size_t)s1 * D + fo);
    const ushort8 v2 = *reinterpret_cast<const ushort8*>(x + (size_t)s2 * D + fo);
    const ushort8 v3 = *reinterpret_cast<const ushort8*>(x + (size_t)s3 * D + fo);
#pragma unroll
    for (int j = 0; j < 8; ++j)
      acc[j] += (b2f(v0[j]) + b2f(v1[j])) + (b2f(v2[j]) + b2f(v3[j]));
  }
  for (; o < end; o += 2) {
    const ushort8 v = *reinterpret_cast<const ushort8*>(x + (size_t)csr[o] * D + fo);
#pragma unroll
    for (int j = 0; j < 8; ++j) acc[j] += b2f(v[j]);
  }

#pragma unroll
  for (int j = 0; j < 8; ++j) acc[j] += __shfl_xor(acc[j], 32, 64);

  if (half == 0) {
    ushort8 ov;
#pragma unroll
    for (int j = 0; j < 8; ++j) ov[j] = f2bf(acc[j]);
    *reinterpret_cast<ushort8*>(out + (size_t)node * D + fo) = ov;
  }
}

// ---------------------------------------------------------------------------
// GEMM core. 1-D grid of 6252 with bijective XCD-chunk swizzle (m204): each
// XCD owns a contiguous col-fast chunk of flat (row,col) space -> the 4
// col-tiles sharing an A-tile run back-to-back on the SAME XCD (A read once,
// L2-reused), and C rows stay XCD-dense.
// ---------------------------------------------------------------------------
constexpr int GEMM_NWG = ((N_NODES + 63) / 64) * 4;   // 6252
constexpr int GEMM_Q   = GEMM_NWG / 8;                // 781
constexpr int GEMM_R   = GEMM_NWG % 8;                // 4
constexpr int CT_PITCH = 72;

template <bool WRITE_C>
__global__ __launch_bounds__(256) void gemm_mfma(const ushort* __restrict__ A,
                                                 const ushort* __restrict__ W,
                                                 const float* __restrict__ bias,
                                                 ushort* __restrict__ C,
                                                 const float* __restrict__ W3,
                                                 float* __restrict__ projp,
                                                 int M) {
  __shared__ __align__(16) ushort As[64 * 256];
  __shared__ __align__(16) ushort Ws[64 * 256];

  const int orig = blockIdx.x;
  const int xcd  = orig & 7;
  const int jj   = orig >> 3;
  const int base_ = (xcd < GEMM_R) ? xcd * (GEMM_Q + 1)
                                   : GEMM_R * (GEMM_Q + 1) + (xcd - GEMM_R) * GEMM_Q;
  const int swz  = base_ + jj;
  const int row0 = (swz >> 2) * 64;
  const int col0 = (swz & 3) * 64;
  const int ct   = swz & 3;

  const int t = threadIdx.x;
  const int w = t >> 6, l = t & 63;

  {
    const float4 zero4 = {0.f, 0.f, 0.f, 0.f};
#pragma unroll
    for (int i = 0; i < 8; ++i) {
      const int chunk = t + i * 256;
      const int r  = chunk >> 5;
      const int kb = (chunk & 31) << 4;
      const int swzb = kb ^ ((r & 7) << 4);
      const int grow = row0 + r;
      float4 av = zero4;
      if (grow < M)
        av = *reinterpret_cast<const float4*>(
            reinterpret_cast<const char*>(A) + (size_t)grow * 512 + kb);
      *reinterpret_cast<float4*>(reinterpret_cast<char*>(As) + r * 512 + swzb) = av;
      const float4 wv = *reinterpret_cast<const float4*>(
          reinterpret_cast<const char*>(W) + (size_t)(col0 + r) * 512 + kb);
      *reinterpret_cast<float4*>(reinterpret_cast<char*>(Ws) + r * 512 + swzb) = wv;
    }
  }
  __syncthreads();

  const int g  = l >> 4;
  const int fr = l & 15;

  frag_cd acc[4];
#pragma unroll
  for (int c = 0; c < 4; ++c) {
    acc[c][0] = 0.f; acc[c][1] = 0.f; acc[c][2] = 0.f; acc[c][3] = 0.f;
  }

  const int arow = w * 16 + fr;
  const char* Asb = reinterpret_cast<const char*>(As);
  const char* Wsb = reinterpret_cast<const char*>(Ws);
#pragma unroll
  for (int ks = 0; ks < 8; ++ks) {
    const int kb = ks * 64 + g * 16;
    const frag_ab af = *reinterpret_cast<const frag_ab*>(
        Asb + arow * 512 + (kb ^ ((arow & 7) << 4)));
#pragma unroll
    for (int c = 0; c < 4; ++c) {
      const int wrow = c * 16 + fr;
      const frag_ab bf = *reinterpret_cast<const frag_ab*>(
          Wsb + wrow * 512 + (kb ^ ((wrow & 7) << 4)));
      acc[c] = __builtin_amdgcn_mfma_f32_16x16x32_bf16(af, bf, acc[c], 0, 0, 0);
    }
  }
  __syncthreads();

  ushort* Ct = As;
#pragma unroll
  for (int c = 0; c < 4; ++c) {
    const int col = c * 16 + fr;
    const float bv = bias[col0 + col];
#pragma unroll
    for (int r = 0; r < 4; ++r) {
      const int rl = w * 16 + g * 4 + r;
      Ct[rl * CT_PITCH + col] = f2bf(fmaxf(acc[c][r] + bv, 0.f));
    }
  }
  __syncthreads();

  if constexpr (WRITE_C) {
#pragma unroll
    for (int i = 0; i < 2; ++i) {
      const int chunk = t + i * 256;
      const int r  = chunk >> 3;
      const int cb = (chunk & 7) << 4;
      const int grow = row0 + r;
      if (grow < M)
        *reinterpret_cast<float4*>(reinterpret_cast<char*>(C) + (size_t)grow * 512 + col0 * 2 + cb) =
            *reinterpret_cast<const float4*>(
                reinterpret_cast<const char*>(Ct) + r * (CT_PITCH * 2) + cb);
    }
  } else {
    // fused proj partials: thread = (row r, quarter q); 16 cols each;
    // 4-lane shuffle reduce, q==0 lane stores float4 (no atomics).
    const int r = t >> 2;
    const int q = t & 3;
    const int grow = row0 + r;
    float pa0 = 0.f, pa1 = 0.f, pb0 = 0.f, pb1 = 0.f;
    if (grow < M) {
      const ushort8 u8a = *reinterpret_cast<const ushort8*>(&Ct[r * CT_PITCH + q * 16]);
      const ushort8 u8b = *reinterpret_cast<const ushort8*>(&Ct[r * CT_PITCH + q * 16 + 8]);
#pragma unroll
      for (int j = 0; j < 16; ++j) {
        const float hv = b2f(j < 8 ? u8a[j] : u8b[j - 8]);
        const int gc = col0 + q * 16 + j;
        pa0 += hv * W3[gc];
        pa1 += hv * W3[512 + gc];
        pb0 += hv * W3[256 + gc];
        pb1 += hv * W3[768 + gc];
      }
    }
    pa0 += __shfl_xor(pa0, 1, 64); pa0 += __shfl_xor(pa0, 2, 64);
    pa1 += __shfl_xor(pa1, 1, 64); pa1 += __shfl_xor(pa1, 2, 64);
    pb0 += __shfl_xor(pb0, 1, 64); pb0 += __shfl_xor(pb0, 2, 64);
    pb1 += __shfl_xor(pb1, 1, 64); pb1 += __shfl_xor(pb1, 2, 64);
    if (q == 0 && grow < M) {
      float4 o; o.x = pa0; o.y = pa1; o.z = pb0; o.w = pb1;
      *reinterpret_cast<float4*>(&projp[((size_t)ct * N_NODES + grow) * 4]) = o;
    }
  }
}

// proj[node] = sum over 4 col-tile slices of projp
__global__ __launch_bounds__(256) void proj_reduce(const float4* __restrict__ projp,
                                                   float4* __restrict__ proj) {
  const int node = blockIdx.x * blockDim.x + threadIdx.x;
  if (node >= N_NODES) return;
  float4 s = projp[node];
#pragma unroll
  for (int ct = 1; ct < 4; ++ct) {
    const float4 v = projp[(size_t)ct * N_NODES + node];
    s.x += v.x; s.y += v.y; s.z += v.z; s.w += v.w;
  }
  proj[node] = s;
}

// logits(p) = (proj[i0].x + proj[i1].z + b3[0], proj[i0].y + proj[i1].w + b3[1])
__global__ __launch_bounds__(256) void pair_lite(const float4* __restrict__ proj,
                                                 const int* __restrict__ idx,
                                                 const float* __restrict__ b3,
                                                 float* __restrict__ out) {
  const int p = blockIdx.x * blockDim.x + threadIdx.x;
  if (p >= N_PAIRS) return;
  const int2 ii = reinterpret_cast<const int2*>(idx)[p];
  const float4 pa = proj[ii.x];
  const float4 pb = proj[ii.y];
  float l0 = pa.x + pb.z + b3[0];
  float l1 = pa.y + pb.w + b3[1];
  const float m = fmaxf(l0, l1);
  const float lse = m + logf(expf(l0 - m) + expf(l1 - m));
  float2 o; o.x = l0 - lse; o.y = l1 - lse;
  reinterpret_cast<float2*>(out)[p] = o;
}

// ---------------------------------------------------------------------------
extern "C" void kernel_launch(void* const* d_in, const int* in_sizes, int n_in,
                              void* d_out, int out_size, void* d_ws, size_t ws_size,
                              hipStream_t stream) {
  const float* x   = (const float*)d_in[0];
  const int*   ei  = (const int*)d_in[1];
  const int*   idx = (const int*)d_in[2];
  const float* W1  = (const float*)d_in[3];
  const float* b1  = (const float*)d_in[4];
  const float* W2  = (const float*)d_in[5];
  const float* b2  = (const float*)d_in[6];
  const float* W3  = (const float*)d_in[7];
  const float* b3  = (const float*)d_in[8];
  float* out = (float*)d_out;

  char* ws = (char*)d_ws;
  ushort* xb    = (ushort*)(ws);                   // 51.2 MB
  ushort* aggb  = (ushort*)(ws + 51200000);        // 51.2 MB
  int*    bucket= (int*)(ws + 51200000);           // 13.12 MB, aliases aggb (build only)
  ushort* hb    = (ushort*)(ws + 102400000);       // 51.2 MB
  // projp/projf alias hb: written during/after gemm2, when hb is dead.
  float* projp  = (float*)(ws + 102400000);        // 4 x 100k x 4 f32 = 6.4 MB
  float* projf  = (float*)(ws + 108800000);        // 1.6 MB
  ushort* W1b   = (ushort*)(ws + 153600000);       // 128 KB
  ushort* W2b   = (ushort*)(ws + 153731072);       // 128 KB
  int* counts   = (int*)(ws + 153862144);          // SCANN ints
  int* cursor   = (int*)(ws + 154263552);
  int* pos      = (int*)(ws + 154664960);
  int* csr      = (int*)(ws + 155066368);          // 12.8 MB
  int* bsum     = (int*)(ws + 169466368);          // 98 ints
  int* bsum2    = (int*)(ws + 169466880);          // 98 ints
  int* rc       = (int*)(ws + 169467392);          // 8 ints

  const dim3 blk(256);
  const size_t feat = (size_t)N_NODES * D;
  constexpr int SCAN_BLOCKS = SCANN / 1024;        // 98
  const dim3 partGrid((N_EDGES + PART_SEG - 1) / PART_SEG);   // 782
  const dim3 flocGrid(NRANGE * FLB);                           // 1024
  const dim3 nodeGrid((N_NODES + 3) / 4);
  const dim3 gemmGrid(GEMM_NWG);                               // 6252, swizzled
  const dim3 nodeThreadGrid((N_NODES + 255) / 256);
  const dim3 pairGrid((N_PAIRS + 255) / 256);

  // ---- converts + zero counts + init rc (one launch) ----
  conv_all<<<dim3(4096), blk, 0, stream>>>((const float4*)x, (const float4*)W1,
                                           (const float4*)W2, (ushort4*)xb,
                                           (ushort4*)W1b, (ushort4*)W2b,
                                           (int4*)counts, rc, (int)(feat / 4));

  // ---- CSR build: fused partition+hist -> hierarchical scan -> local fill ----
  part_hist<<<partGrid, blk, 0, stream>>>(ei, counts, rc, bucket);
  scan_block_k<<<dim3(SCAN_BLOCKS), dim3(1024), 0, stream>>>(counts, cursor, bsum);
  scan_small<<<1, 1024, 0, stream>>>(bsum, bsum2, SCAN_BLOCKS);
  scan_add_k<<<dim3(SCAN_BLOCKS), dim3(1024), 0, stream>>>(cursor, pos, bsum2);
  fill_local<<<flocGrid, blk, 0, stream>>>(bucket, rc, pos, csr);

  // ---- layer 1 ----
  gather_agg_bf16<<<nodeGrid, blk, 0, stream>>>(xb, csr, cursor, counts, aggb);
  gemm_mfma<true><<<gemmGrid, blk, 0, stream>>>(aggb, W1b, b1, hb, nullptr, nullptr, N_NODES);

  // ---- layer 2 (fused head projection, no hb write) ----
  gather_agg_bf16<<<nodeGrid, blk, 0, stream>>>(hb, csr, cursor, counts, aggb);
  gemm_mfma<false><<<gemmGrid, blk, 0, stream>>>(aggb, W2b, b2, nullptr, W3, projp, N_NODES);

  // ---- pair head ----
  proj_reduce<<<nodeThreadGrid, blk, 0, stream>>>((const float4*)projp, (float4*)projf);
  pair_lite<<<pairGrid, blk, 0, stream>>>((const float4*)projf, idx, b3, out);
}